// Round 1
// baseline (352.667 us; speedup 1.0000x reference)
//
#include <hip/hip_runtime.h>
#include <stdint.h>

#define NSUP 1024
#define NQRY 32768
#define DIM  64
#define NCLS 64

typedef float  f32x4  __attribute__((ext_vector_type(4)));
typedef short  s16x8  __attribute__((ext_vector_type(8)));
typedef __bf16 bf16x8 __attribute__((ext_vector_type(8)));

static __device__ __forceinline__ unsigned short f2bf(float f) {
  unsigned u = __float_as_uint(f);
  u += 0x7FFFu + ((u >> 16) & 1u);           // round-to-nearest-even
  return (unsigned short)(u >> 16);
}
static __device__ __forceinline__ float bf2f(unsigned short s) {
  return __uint_as_float(((unsigned)s) << 16);
}

// ---------------- Kernel 1: normalize queries -> bf16 ----------------
// wave handles 4 rows; lane (h=lane>>4 -> row-in-group, c=lane&15 -> 4-float chunk)
__global__ __launch_bounds__(256) void prep_queries(const float* __restrict__ Xq,
                                                    unsigned short* __restrict__ Ybf) {
  int tid  = threadIdx.x;
  int lane = tid & 63;
  int wave = tid >> 6;
  int row  = blockIdx.x * 16 + wave * 4 + (lane >> 4);
  int cb   = (lane & 15) * 4;
  float4 v = *(const float4*)(Xq + row * 64 + cb);
  float ss = v.x * v.x + v.y * v.y + v.z * v.z + v.w * v.w;
  ss += __shfl_xor(ss, 1);
  ss += __shfl_xor(ss, 2);
  ss += __shfl_xor(ss, 4);
  ss += __shfl_xor(ss, 8);
  float inv = 1.0f / fmaxf(sqrtf(ss), 1e-12f);
  unsigned short a = f2bf(v.x * inv), b = f2bf(v.y * inv);
  unsigned short c = f2bf(v.z * inv), d = f2bf(v.w * inv);
  uint2 o;
  o.x = (unsigned)a | ((unsigned)b << 16);
  o.y = (unsigned)c | ((unsigned)d << 16);
  *(uint2*)(Ybf + row * 64 + cb) = o;
}

// ---------------- Kernel 2: fit (one block per class) ----------------
__global__ __launch_bounds__(256) void fit_classes(
    const float* __restrict__ Xs, const int* __restrict__ ys,
    const float* __restrict__ mg, const float* __restrict__ Sg,
    const float* __restrict__ nug, const float* __restrict__ kapg,
    unsigned short* __restrict__ Abf, float* __restrict__ AmuG,
    float* __restrict__ muAmuG) {
  __shared__ int   yls[NSUP];
  __shared__ float Sls[64 * 66];
  __shared__ float xsch[16][64];
  __shared__ float mls[64];
  __shared__ float muls[64];
  __shared__ float Als[64 * 66];
  __shared__ float fcol[64];
  __shared__ float prow[64];
  __shared__ int   lst[NSUP];
  __shared__ int   cnts[2];

  int tid = threadIdx.x;
  int j   = blockIdx.x;

  for (int i = tid; i < NSUP; i += 256) yls[i] = ys[i];
  for (int i = tid; i < 4096; i += 256) Sls[(i >> 6) * 66 + (i & 63)] = Sg[i];
  if (tid < 64) mls[tid] = mg[tid];
  __syncthreads();

  // wave 0: build match list + counts (Nj and the reference's N0 = count of class 0)
  if (tid < 64) {
    int lane = tid;
    int cnt = 0, n0 = 0;
    for (int b = 0; b < NSUP; b += 64) {
      int yv = yls[b + lane];
      unsigned long long mj = __ballot(yv == j);
      unsigned long long m0 = __ballot(yv == 0);
      if (lane == 0) {
        n0 += (int)__popcll(m0);
        while (mj) { int bit = __builtin_ctzll(mj); lst[cnt++] = b + bit; mj &= mj - 1; }
      }
    }
    if (lane == 0) { cnts[0] = cnt; cnts[1] = n0; }
  }
  __syncthreads();
  int cnt = cnts[0], n0 = cnts[1];

  // accumulate Ssum (thread t: row r_=t&63, cols c0..c0+15) and sum_x
  int r_   = tid & 63;
  int cblk = tid >> 6;
  int c0   = cblk * 16;
  float accS[16];
#pragma unroll
  for (int i = 0; i < 16; ++i) accS[i] = 0.f;
  float sumx = 0.f;

  for (int s0 = 0; s0 < cnt; s0 += 16) {
    int nch = min(16, cnt - s0);
    if (tid < 64) {
      for (int s = 0; s < nch; ++s) {
        int n = lst[s0 + s];
        float v = Xs[n * 64 + tid];
        float ss = v * v;
        ss += __shfl_xor(ss, 1);  ss += __shfl_xor(ss, 2);
        ss += __shfl_xor(ss, 4);  ss += __shfl_xor(ss, 8);
        ss += __shfl_xor(ss, 16); ss += __shfl_xor(ss, 32);
        float inv = 1.0f / fmaxf(sqrtf(ss), 1e-12f);
        xsch[s][tid] = v * inv;
      }
    }
    __syncthreads();
    for (int s = 0; s < nch; ++s) {
      float a = xsch[s][r_];
      if (cblk == 0) sumx += a;
#pragma unroll
      for (int i = 0; i < 16; ++i) accS[i] += a * xsch[s][c0 + i];
    }
    __syncthreads();
  }

  float kap = kapg[0];
  float nuv = nug[0];
  if (tid < 64) {
    float Njf = (float)cnt, N0f = (float)n0;
    float mean = sumx / Njf;
    float head = kap / (kap + N0f) * mls[tid] + N0f / (kap + N0f);
    muls[tid] = head * mean;
  }
  __syncthreads();

  // sigma = left * (middle + Ssum + kappa*m m^T - (kappa+Nj) mu mu^T)
  {
    float Njf  = (float)cnt;
    float left = 1.0f / (nuv + Njf + (float)DIM + 2.0f);
    float kn   = kap + Njf;
    float mr   = mls[r_], mur = muls[r_];
#pragma unroll 1
    for (int i = 0; i < 16; ++i) {
      int c = c0 + i;
      int kmax = min(r_, c);
      float mid = 0.f;
      for (int k = 0; k <= kmax; ++k) mid += Sls[r_ * 66 + k] * Sls[c * 66 + k];
      float val = mid + accS[i] + kap * mr * mls[c] - kn * mur * muls[c];
      Als[r_ * 66 + c] = left * val;
    }
  }
  __syncthreads();

  // in-place Gauss-Jordan sweep (SPD, no pivoting). thread: row rr, 16-col chunk
  int rr  = tid >> 2;
  int cq  = tid & 3;
  int cc0 = cq * 16;
  for (int p = 0; p < 64; ++p) {
    if (cq == (p >> 4)) fcol[rr] = Als[rr * 66 + p];
    if (rr == p) {
#pragma unroll
      for (int i = 0; i < 16; ++i) prow[cc0 + i] = Als[p * 66 + cc0 + i];
    }
    __syncthreads();
    float d  = 1.0f / fcol[p];
    float fr = fcol[rr];
#pragma unroll
    for (int i = 0; i < 16; ++i) {
      int c = cc0 + i;
      float q  = prow[c] * d;
      float ar = Als[rr * 66 + c];
      float res;
      if (rr == p) res = (c == p) ? d : q;
      else         res = (c == p) ? (-fr * d) : fmaf(-fr, q, ar);
      Als[rr * 66 + c] = res;
    }
    __syncthreads();
  }

  // A = 0.7*inv + 0.3*I -> bf16, row-major [j][r][c]
  {
    unsigned short tmp[16];
#pragma unroll
    for (int i = 0; i < 16; ++i) {
      int c = cc0 + i;
      float a = 0.7f * Als[rr * 66 + c] + ((c == rr) ? 0.3f : 0.0f);
      tmp[i] = f2bf(a);
    }
    uint4 w0, w1;
    w0.x = (unsigned)tmp[0]  | ((unsigned)tmp[1]  << 16);
    w0.y = (unsigned)tmp[2]  | ((unsigned)tmp[3]  << 16);
    w0.z = (unsigned)tmp[4]  | ((unsigned)tmp[5]  << 16);
    w0.w = (unsigned)tmp[6]  | ((unsigned)tmp[7]  << 16);
    w1.x = (unsigned)tmp[8]  | ((unsigned)tmp[9]  << 16);
    w1.y = (unsigned)tmp[10] | ((unsigned)tmp[11] << 16);
    w1.z = (unsigned)tmp[12] | ((unsigned)tmp[13] << 16);
    w1.w = (unsigned)tmp[14] | ((unsigned)tmp[15] << 16);
    *(uint4*)(Abf + j * 4096 + rr * 64 + cc0)     = w0;
    *(uint4*)(Abf + j * 4096 + rr * 64 + cc0 + 8) = w1;
  }

  // Amu = A*mu (f32), muAmu = mu.Amu
  if (tid < 64) {
    float s = 0.f;
    for (int c = 0; c < 64; ++c) s += Als[tid * 66 + c] * muls[c];
    float amu = 0.7f * s + 0.3f * muls[tid];
    AmuG[j * 64 + tid] = amu;
    float t2 = amu * muls[tid];
    t2 += __shfl_xor(t2, 1);  t2 += __shfl_xor(t2, 2);
    t2 += __shfl_xor(t2, 4);  t2 += __shfl_xor(t2, 8);
    t2 += __shfl_xor(t2, 16); t2 += __shfl_xor(t2, 32);
    if (tid == 0) muAmuG[j] = t2;
  }
}

// ---------------- Kernel 3: predict (MFMA) ----------------
// grid 256 = 64 query-tiles x 4 class-quarters; block 512 = 8 waves x 64 queries
__global__ __launch_bounds__(512, 2) void predict_kernel(
    const unsigned short* __restrict__ Ybf, const unsigned short* __restrict__ Abf,
    const float* __restrict__ AmuG, const float* __restrict__ muAmuG,
    float* __restrict__ out) {
  __shared__ __align__(16) unsigned short Albuf[2][4096];
  int tid   = threadIdx.x;
  int lane  = tid & 63;
  int wave  = tid >> 6;
  int qt    = blockIdx.x >> 2;
  int cg    = blockIdx.x & 3;
  int cbase = cg * 16;
  int qbase = qt * 512 + wave * 64;
  int c = lane & 15, h = lane >> 4;

  // hoist query fragments for this wave's 64 queries
  s16x8 bfr[4][2];
  float yc[4][4][4];
#pragma unroll
  for (int nt = 0; nt < 4; ++nt) {
    const unsigned short* yrow = Ybf + (size_t)(qbase + nt * 16 + c) * 64;
#pragma unroll
    for (int ks = 0; ks < 2; ++ks)
      bfr[nt][ks] = *(const s16x8*)(yrow + ks * 32 + h * 8);
#pragma unroll
    for (int et = 0; et < 4; ++et) {
      uint2 u = *(const uint2*)(yrow + et * 16 + h * 4);
      yc[nt][et][0] = bf2f((unsigned short)(u.x & 0xFFFFu));
      yc[nt][et][1] = bf2f((unsigned short)(u.x >> 16));
      yc[nt][et][2] = bf2f((unsigned short)(u.y & 0xFFFFu));
      yc[nt][et][3] = bf2f((unsigned short)(u.y >> 16));
    }
  }

  // prologue: stage first class into buffer 0 (reg-staged)
  {
    uint4 v = *(const uint4*)(Abf + (size_t)cbase * 4096 + tid * 8);
    *(uint4*)&Albuf[0][tid * 8] = v;
  }
  __syncthreads();

  float sc[16];
  int cur = 0;
#pragma unroll
  for (int jj = 0; jj < 16; ++jj) {
    int jcls = cbase + jj;
    uint4 stg;
    if (jj < 15) stg = *(const uint4*)(Abf + (size_t)(jcls + 1) * 4096 + tid * 8);

    s16x8 af[4][2];
#pragma unroll
    for (int et = 0; et < 4; ++et)
#pragma unroll
      for (int ks = 0; ks < 2; ++ks)
        af[et][ks] = *(const s16x8*)&Albuf[cur][(et * 16 + c) * 64 + ks * 32 + h * 8];

    float am[4][4];
#pragma unroll
    for (int et = 0; et < 4; ++et) {
      float4 a4 = *(const float4*)(AmuG + jcls * 64 + et * 16 + h * 4);
      am[et][0] = a4.x; am[et][1] = a4.y; am[et][2] = a4.z; am[et][3] = a4.w;
    }
    float mua = muAmuG[jcls];

    float p[4];
#pragma unroll
    for (int nt = 0; nt < 4; ++nt) {
      f32x4 acc[4];
#pragma unroll
      for (int et = 0; et < 4; ++et) acc[et] = (f32x4){0.f, 0.f, 0.f, 0.f};
#pragma unroll
      for (int ks = 0; ks < 2; ++ks)
#pragma unroll
        for (int et = 0; et < 4; ++et)
          acc[et] = __builtin_amdgcn_mfma_f32_16x16x32_bf16(
              __builtin_bit_cast(bf16x8, af[et][ks]),
              __builtin_bit_cast(bf16x8, bfr[nt][ks]), acc[et], 0, 0, 0);
      float s = 0.f;
#pragma unroll
      for (int et = 0; et < 4; ++et)
#pragma unroll
        for (int r = 0; r < 4; ++r)
          s += (acc[et][r] - 2.0f * am[et][r]) * yc[nt][et][r];
      s += __shfl_xor(s, 16);
      s += __shfl_xor(s, 32);
      p[nt] = s;
    }
    float ps = (h == 0) ? p[0] : (h == 1) ? p[1] : (h == 2) ? p[2] : p[3];
    sc[jj] = -ps - mua;

    if (jj < 15) *(uint4*)&Albuf[cur ^ 1][tid * 8] = stg;
    __syncthreads();
    cur ^= 1;
  }

  float* orow = out + (size_t)(qbase + lane) * 64 + cbase;
#pragma unroll
  for (int k = 0; k < 4; ++k) {
    f32x4 v = { sc[4 * k], sc[4 * k + 1], sc[4 * k + 2], sc[4 * k + 3] };
    *(f32x4*)(orow + 4 * k) = v;
  }
}

extern "C" void kernel_launch(void* const* d_in, const int* in_sizes, int n_in,
                              void* d_out, int out_size, void* d_ws, size_t ws_size,
                              hipStream_t stream) {
  const float* Xs   = (const float*)d_in[0];
  const int*   ys   = (const int*)d_in[1];
  const float* Xq   = (const float*)d_in[2];
  const float* mg   = (const float*)d_in[3];
  const float* Sg   = (const float*)d_in[4];
  const float* nug  = (const float*)d_in[5];
  const float* kapg = (const float*)d_in[6];
  float* out = (float*)d_out;

  unsigned short* Ybf = (unsigned short*)d_ws;              // NQ*64 bf16 = 4 MB
  unsigned short* Abf = Ybf + (size_t)NQRY * 64;            // 64*4096 bf16 = 512 KB
  float* AmuG   = (float*)(Abf + (size_t)NCLS * 4096);      // 64*64 f32
  float* muAmuG = AmuG + NCLS * 64;                         // 64 f32

  prep_queries<<<dim3(NQRY / 16), dim3(256), 0, stream>>>(Xq, Ybf);
  fit_classes<<<dim3(NCLS), dim3(256), 0, stream>>>(Xs, ys, mg, Sg, nug, kapg,
                                                    Abf, AmuG, muAmuG);
  predict_kernel<<<dim3(256), dim3(512), 0, stream>>>(Ybf, Abf, AmuG, muAmuG, out);
}